// Round 4
// baseline (1044.286 us; speedup 1.0000x reference)
//
#include <hip/hip_runtime.h>
#include <hip/hip_bf16.h>
#include <math.h>

// ---------------------------------------------------------------------------
// VQ quantizer:
//   in[0] = z        (16,256,32,32) fp32   -> N=16384 vectors of C=256
//   in[1] = codebook (8192,256)     fp32
//   out   = [ z_q (B,C,H,W) 4194304 | loss | ortho | perplexity | idx(16384) as float ]
//
// idx strategy (two-stage, provably matching the R2/R3 passing semantics):
//   Stage A: bf16 MFMA GEMM approximating dot(z_n, e_j); per (n, 128-j tile)
//            store tilemin = -2*max_j(dot_approx).  Worst-case approx error
//            per dot <= 2^-8 * ||z|| ||e|| <= 7.7e-5  ->  s-error <= 1.6e-4.
//   Stage B: rowmin = min_jt tilemin; for tiles with tilemin <= rowmin + 6e-4
//            recompute the EXACT fp32 chain (k-ascending fmaf, epilogue
//            t = A_n + ce_j; d = fmaf(-2, acc, t)) == R2/R3 bit-identical;
//            argmin with lowest-index tie-break.  Margin 6e-4 > 2*maxerr +
//            ulp(d) -> the true winner and all exact grid-ties are examined.
// ---------------------------------------------------------------------------

#define N_E     8192
#define C_DIM   256
#define N_VEC   16384            // 16*32*32
#define N_ELEM  4194304          // 16*256*32*32
#define MARGIN  6.0e-4f

// ws layout (bytes)
#define WS_COUNTS   0            // int[8192]                 32768
#define WS_M        32768        // float[65536]              262144
#define WS_ACCUM    294912       // double[2]                 16
#define WS_RN       294928       // float[8192]               32768
#define WS_CE       327696       // float[8192]               32768
#define WS_A        360464       // float[16384]              65536
#define WS_IDXI     426000       // int[16384]                65536
#define WS_TILEMIN  491536       // float[16384*64]           4194304
#define WS_ZT       4685840      // float[16384*256]          16777216
#define WS_ZBF      21463056     // ushort[16384*256]         8388608
#define WS_CBBF     29851664     // ushort[8192*256]          4194304
#define WS_ZERO_BYTES 294928     // counts + M + accum

typedef short short8v __attribute__((ext_vector_type(8)));
typedef float f32x4  __attribute__((ext_vector_type(4)));

__device__ inline unsigned short f2bf(float f) {       // RNE fp32->bf16 (no NaN in data)
    unsigned int x = __float_as_uint(f);
    return (unsigned short)((x + 0x7fffu + ((x >> 16) & 1u)) >> 16);
}

// ---------------------------------------------------------------------------
// codebook row squared norms + reciprocal norms (unchanged bits vs R2/R3)
__global__ __launch_bounds__(256) void k_sqnorm(const float* __restrict__ cb,
                                                float* __restrict__ ce,
                                                float* __restrict__ rn) {
    int j = blockIdx.x;
    int tid = threadIdx.x;
    float v = cb[(size_t)j * C_DIM + tid];
    float s = v * v;
    #pragma unroll
    for (int off = 32; off > 0; off >>= 1) s += __shfl_down(s, off, 64);
    __shared__ float sh[4];
    if ((tid & 63) == 0) sh[tid >> 6] = s;
    __syncthreads();
    if (tid == 0) {
        float t = sh[0] + sh[1] + sh[2] + sh[3];
        ce[j] = t;
        rn[j] = 1.0f / sqrtf(t);
    }
}

// ---------------------------------------------------------------------------
// z row squared norms (unchanged bits vs R2/R3)
__global__ __launch_bounds__(256) void k_znorm(const float* __restrict__ z,
                                               float* __restrict__ A) {
    int n = blockIdx.x * 256 + threadIdx.x;      // n = b*1024 + hw
    int b = n >> 10, hw = n & 1023;
    const float* zp = z + (size_t)b * 262144 + hw;
    float a = 0.0f;
    #pragma unroll 8
    for (int c = 0; c < C_DIM; ++c) {
        float v = zp[(size_t)c * 1024];
        a = fmaf(v, v, a);
    }
    A[n] = a;
}

// ---------------------------------------------------------------------------
// transpose z -> zT (fp32, [n][k], exact copy) and zbf (bf16 bits, [n][k]).
// reads coalesced along hw; per-thread sequential writes merge in L2.
__global__ __launch_bounds__(256) void k_transpose(const float* __restrict__ z,
                                                   float* __restrict__ zT,
                                                   unsigned short* __restrict__ zbf) {
    int n = blockIdx.x * 256 + threadIdx.x;
    int b = n >> 10, hw = n & 1023;
    int c0 = blockIdx.y * 64;
    const float* zp = z + (size_t)b * 262144 + hw;
    #pragma unroll 8
    for (int c = c0; c < c0 + 64; ++c) {
        float v = zp[(size_t)c * 1024];
        zT[(size_t)n * C_DIM + c] = v;
        zbf[(size_t)n * C_DIM + c] = f2bf(v);
    }
}

// ---------------------------------------------------------------------------
// codebook fp32 -> bf16 bits
__global__ __launch_bounds__(256) void k_cvtcb(const float* __restrict__ cb,
                                               unsigned short* __restrict__ cbbf) {
    size_t i = ((size_t)blockIdx.x * 256 + threadIdx.x) * 4;
    float4 v = *(const float4*)&cb[i];
    ushort4 u = { f2bf(v.x), f2bf(v.y), f2bf(v.z), f2bf(v.w) };
    *(ushort4*)&cbbf[i] = u;
}

// ---------------------------------------------------------------------------
// Stage A: bf16 MFMA GEMM, 128n x 128j per block (4 waves, 2x2), K=256 in 4
// chunks of 64.  Epilogue: tilemin[n][bx] = -2 * max_j dot_approx.
__global__ __launch_bounds__(256) void k_mfma(const unsigned short* __restrict__ zbf,
                                              const unsigned short* __restrict__ cbbf,
                                              float* __restrict__ tilemin) {
    __shared__ unsigned short As[128 * 72];   // [n][k], pad 72 -> 2-way max
    __shared__ unsigned short Bs[128 * 72];   // [j][k]
    __shared__ float smin[128][2];

    const int tid = threadIdx.x;
    const int bx = blockIdx.x, by = blockIdx.y;
    const int n0 = by * 128, j0 = bx * 128;
    const int wave = tid >> 6, lane = tid & 63;
    const int wx = wave & 1, wy = wave >> 1;      // wave tile: 64n x 64j
    const int g = lane >> 4, c = lane & 15;
    const int kg = tid & 7, nl = tid >> 3;        // staging: 8 k-groups x 32 rows

    f32x4 acc[4][4];
    #pragma unroll
    for (int i = 0; i < 4; ++i)
        #pragma unroll
        for (int j = 0; j < 4; ++j) acc[i][j] = (f32x4){0.f, 0.f, 0.f, 0.f};

    for (int kc = 0; kc < C_DIM; kc += 64) {
        __syncthreads();
        #pragma unroll
        for (int p = 0; p < 4; ++p) {
            int row = nl + 32 * p;
            *(short8v*)&As[row * 72 + kg * 8] =
                *(const short8v*)&zbf[(size_t)(n0 + row) * C_DIM + kc + kg * 8];
            *(short8v*)&Bs[row * 72 + kg * 8] =
                *(const short8v*)&cbbf[(size_t)(j0 + row) * C_DIM + kc + kg * 8];
        }
        __syncthreads();

        #pragma unroll
        for (int kk = 0; kk < 64; kk += 32) {
            short8v a[4], b[4];
            #pragma unroll
            for (int f = 0; f < 4; ++f)
                a[f] = *(const short8v*)&As[(wy * 64 + f * 16 + c) * 72 + kk + g * 8];
            #pragma unroll
            for (int f = 0; f < 4; ++f)
                b[f] = *(const short8v*)&Bs[(wx * 64 + f * 16 + c) * 72 + kk + g * 8];
            #pragma unroll
            for (int nf = 0; nf < 4; ++nf)
                #pragma unroll
                for (int jf = 0; jf < 4; ++jf)
                    acc[nf][jf] = __builtin_amdgcn_mfma_f32_16x16x32_bf16(
                        a[nf], b[jf], acc[nf][jf], 0, 0, 0);
        }
    }

    // C layout: col = lane&15 (j), row = (lane>>4)*4 + reg (n).  max over j.
    #pragma unroll
    for (int nf = 0; nf < 4; ++nf) {
        #pragma unroll
        for (int r = 0; r < 4; ++r) {
            float mx = acc[nf][0][r];
            #pragma unroll
            for (int jf = 1; jf < 4; ++jf) mx = fmaxf(mx, acc[nf][jf][r]);
            #pragma unroll
            for (int off = 1; off < 16; off <<= 1)
                mx = fmaxf(mx, __shfl_xor(mx, off, 64));
            if (c == 0) smin[wy * 64 + nf * 16 + g * 4 + r][wx] = -2.0f * mx;
        }
    }
    __syncthreads();
    if (tid < 128)
        tilemin[(size_t)(n0 + tid) * 64 + bx] = fminf(smin[tid][0], smin[tid][1]);
}

// ---------------------------------------------------------------------------
// Stage B: exact refine.  One block per row n.  Flags tiles within MARGIN of
// rowmin, recomputes the exact R2/R3 fp32 chain for their 128 j's, argmin
// with lowest-index tie-break, writes idx + histogram.
__global__ __launch_bounds__(256) void k_refine(const float* __restrict__ zT,
                                                const float* __restrict__ cb,
                                                const float* __restrict__ ce,
                                                const float* __restrict__ A,
                                                const float* __restrict__ tilemin,
                                                int* __restrict__ idxi,
                                                float* __restrict__ out_idx,
                                                int* __restrict__ counts) {
    const int n = blockIdx.x;
    const int tid = threadIdx.x;
    __shared__ float zrow[256];
    __shared__ float tm[64];
    __shared__ float s_rm;
    __shared__ unsigned long long wkey[4];

    zrow[tid] = zT[(size_t)n * C_DIM + tid];
    if (tid < 64) tm[tid] = tilemin[(size_t)n * 64 + tid];
    __syncthreads();
    if (tid < 64) {
        float v = tm[tid];
        #pragma unroll
        for (int off = 32; off > 0; off >>= 1) v = fminf(v, __shfl_xor(v, off, 64));
        if (tid == 0) s_rm = v;
    }
    __syncthreads();
    const float thr = s_rm + MARGIN;
    const float An = A[n];

    unsigned long long best = ~0ull;
    for (int jt = 0; jt < 64; ++jt) {
        if (tm[jt] > thr) continue;                  // block-uniform branch
        if (tid < 128) {
            const int j = jt * 128 + tid;
            const float* e = cb + (size_t)j * C_DIM;
            float acc = 0.0f;
            #pragma unroll 4
            for (int k = 0; k < C_DIM; k += 4) {     // exact k-ascending chain
                float4 ev = *(const float4*)&e[k];
                acc = fmaf(zrow[k],     ev.x, acc);
                acc = fmaf(zrow[k + 1], ev.y, acc);
                acc = fmaf(zrow[k + 2], ev.z, acc);
                acc = fmaf(zrow[k + 3], ev.w, acc);
            }
            float t = An + ce[j];                    // == R2/R3 epilogue bits
            float d = fmaf(-2.0f, acc, t);
            unsigned int sd = __float_as_uint(d);
            sd = (sd & 0x80000000u) ? ~sd : (sd | 0x80000000u);
            unsigned long long key = ((unsigned long long)sd << 32) | (unsigned)j;
            best = key < best ? key : best;
        }
    }
    #pragma unroll
    for (int off = 32; off > 0; off >>= 1) {
        unsigned long long o = __shfl_xor(best, off, 64);
        best = o < best ? o : best;
    }
    if ((tid & 63) == 0) wkey[tid >> 6] = best;
    __syncthreads();
    if (tid == 0) {
        unsigned long long k = wkey[0];
        #pragma unroll
        for (int w = 1; w < 4; ++w) k = wkey[w] < k ? wkey[w] : k;
        int idx = (int)(k & 0xFFFFFFFFull);
        idxi[n] = idx;
        out_idx[n] = (float)idx;
        atomicAdd(&counts[idx], 1);
    }
}

// ---------------------------------------------------------------------------
// gather z_q (write in (B,C,H,W) layout) + fp64 SSE reduction for the loss
__global__ __launch_bounds__(256) void k_gather(const float* __restrict__ z,
                                                const float* __restrict__ cb,
                                                const int* __restrict__ idxi,
                                                float* __restrict__ out,
                                                double* __restrict__ sse) {
    int bh = blockIdx.x;                 // b*32 + h
    int b = bh >> 5, h = bh & 31;
    int tid = threadIdx.x;
    int w = tid & 31, cy = tid >> 5;
    int n = b * 1024 + h * 32 + w;
    int jid = idxi[n];
    const float* cbr = cb + (size_t)jid * C_DIM;
    size_t zb = (size_t)b * 262144 + h * 32 + w;

    double acc = 0.0;
    #pragma unroll 4
    for (int cc = 0; cc < 32; ++cc) {
        int c = cc * 8 + cy;
        float e = cbr[c];
        size_t zi = zb + (size_t)c * 1024;
        float d = e - z[zi];
        out[zi] = e;
        acc += (double)(d * d);
    }
    #pragma unroll
    for (int off = 32; off > 0; off >>= 1) acc += __shfl_down(acc, off, 64);
    __shared__ double sh[4];
    if ((tid & 63) == 0) sh[tid >> 6] = acc;
    __syncthreads();
    if (tid == 0) atomicAdd(sse, sh[0] + sh[1] + sh[2] + sh[3]);
}

// ---------------------------------------------------------------------------
// Gram matrix M = Wn^T Wn  (256x256), j-split with float atomics
__global__ __launch_bounds__(256) void k_gram(const float* __restrict__ cb,
                                              const float* __restrict__ rn,
                                              float* __restrict__ M) {
    __shared__ float aT[64][68];
    __shared__ float bT[64][68];
    int k0 = blockIdx.x * 64, l0 = blockIdx.y * 64;
    int jc0 = blockIdx.z * 256;
    int tid = threadIdx.x;
    int tk = tid & 15, tl = tid >> 4;
    float acc[4][4];
    #pragma unroll
    for (int i = 0; i < 4; ++i)
        #pragma unroll
        for (int l = 0; l < 4; ++l) acc[i][l] = 0.0f;

    for (int jc = jc0; jc < jc0 + 256; jc += 64) {
        __syncthreads();
        {
            int kk = tid & 63, jj0 = tid >> 6;
            #pragma unroll
            for (int p = 0; p < 16; ++p) {
                int jj = p * 4 + jj0;
                float r = rn[jc + jj];
                const float* row = cb + (size_t)(jc + jj) * C_DIM;
                aT[jj][kk] = row[k0 + kk] * r;
                bT[jj][kk] = row[l0 + kk] * r;
            }
        }
        __syncthreads();
        #pragma unroll 8
        for (int jj = 0; jj < 64; ++jj) {
            float4 av = *(const float4*)&aT[jj][tk * 4];
            float4 bv = *(const float4*)&bT[jj][tl * 4];
            float a4[4] = {av.x, av.y, av.z, av.w};
            float b4[4] = {bv.x, bv.y, bv.z, bv.w};
            #pragma unroll
            for (int i = 0; i < 4; ++i)
                #pragma unroll
                for (int l = 0; l < 4; ++l)
                    acc[i][l] = fmaf(a4[i], b4[l], acc[i][l]);
        }
    }
    #pragma unroll
    for (int i = 0; i < 4; ++i)
        #pragma unroll
        for (int l = 0; l < 4; ++l)
            atomicAdd(&M[(size_t)(k0 + tk * 4 + i) * C_DIM + l0 + tl * 4 + l], acc[i][l]);
}

// ---------------------------------------------------------------------------
// finalize scalars: loss, ortho = (||M||_F^2 - n_e)/n_e^2, perplexity
__global__ __launch_bounds__(256) void k_final(const float* __restrict__ M,
                                               const int* __restrict__ counts,
                                               const double* __restrict__ accum,
                                               float* __restrict__ out_scalars) {
    int tid = threadIdx.x;
    __shared__ double sh[4];

    double s = 0.0;
    for (int i = tid; i < C_DIM * C_DIM; i += 256) {
        double m = M[i];
        s += m * m;
    }
    #pragma unroll
    for (int off = 32; off > 0; off >>= 1) s += __shfl_down(s, off, 64);
    if ((tid & 63) == 0) sh[tid >> 6] = s;
    __syncthreads();
    double S = sh[0] + sh[1] + sh[2] + sh[3];
    __syncthreads();

    double H = 0.0;
    for (int j = tid; j < N_E; j += 256) {
        double p = counts[j] * (1.0 / (double)N_VEC);
        H += p * log(p + 1e-10);
    }
    #pragma unroll
    for (int off = 32; off > 0; off >>= 1) H += __shfl_down(H, off, 64);
    if ((tid & 63) == 0) sh[tid >> 6] = H;
    __syncthreads();

    if (tid == 0) {
        double Hs = sh[0] + sh[1] + sh[2] + sh[3];
        out_scalars[0] = (float)(1.25 * accum[0] / (double)N_ELEM);        // loss
        out_scalars[1] = (float)((S - (double)N_E) / ((double)N_E * N_E)); // ortho
        out_scalars[2] = (float)exp(-Hs);                                  // perplexity
    }
}

// ---------------------------------------------------------------------------
extern "C" void kernel_launch(void* const* d_in, const int* in_sizes, int n_in,
                              void* d_out, int out_size, void* d_ws, size_t ws_size,
                              hipStream_t stream) {
    (void)in_sizes; (void)n_in; (void)out_size; (void)ws_size;
    const float* z  = (const float*)d_in[0];
    const float* cb = (const float*)d_in[1];
    float* out = (float*)d_out;

    char* ws = (char*)d_ws;
    int* counts            = (int*)(ws + WS_COUNTS);
    float* M               = (float*)(ws + WS_M);
    double* accum          = (double*)(ws + WS_ACCUM);
    float* rn              = (float*)(ws + WS_RN);
    float* ce              = (float*)(ws + WS_CE);
    float* A               = (float*)(ws + WS_A);
    int* idxi              = (int*)(ws + WS_IDXI);
    float* tilemin         = (float*)(ws + WS_TILEMIN);
    float* zT              = (float*)(ws + WS_ZT);
    unsigned short* zbf    = (unsigned short*)(ws + WS_ZBF);
    unsigned short* cbbf   = (unsigned short*)(ws + WS_CBBF);

    float* out_scalars = out + N_ELEM;       // loss, ortho, perplexity
    float* out_idx     = out + N_ELEM + 3;   // 16384 idx as float

    hipMemsetAsync(ws, 0, WS_ZERO_BYTES, stream);

    k_sqnorm<<<N_E, 256, 0, stream>>>(cb, ce, rn);
    k_znorm<<<N_VEC / 256, 256, 0, stream>>>(z, A);
    k_transpose<<<dim3(N_VEC / 256, 4), 256, 0, stream>>>(z, zT, zbf);
    k_cvtcb<<<(N_E * C_DIM) / (256 * 4), 256, 0, stream>>>(cb, cbbf);
    k_mfma<<<dim3(N_E / 128, N_VEC / 128), 256, 0, stream>>>(zbf, cbbf, tilemin);
    k_refine<<<N_VEC, 256, 0, stream>>>(zT, cb, ce, A, tilemin, idxi, out_idx, counts);
    k_gather<<<512, 256, 0, stream>>>(z, cb, idxi, out, accum);
    k_gram<<<dim3(4, 4, 32), 256, 0, stream>>>(cb, rn, M);
    k_final<<<1, 256, 0, stream>>>(M, counts, accum, out_scalars);
}

// Round 5
// 562.062 us; speedup vs baseline: 1.8580x; 1.8580x over previous
//
#include <hip/hip_runtime.h>
#include <hip/hip_bf16.h>
#include <math.h>

// ---------------------------------------------------------------------------
// VQ quantizer:
//   in[0] = z        (16,256,32,32) fp32   -> N=16384 vectors of C=256
//   in[1] = codebook (8192,256)     fp32
//   out   = [ z_q (B,C,H,W) 4194304 | loss | ortho | perplexity | idx(16384) as float ]
//
// idx strategy (two-stage, bit-matching the R2/R3/R4 passing semantics):
//   Stage A: bf16 MFMA GEMM; per (128-j tile, n) store
//            tilemin[t][n] = -2*max_j dot_approx.   |s_hat - s| <= 1.54e-4.
//   Stage B (tile-centric): per row, rowmin = min_t tilemin; every tile with
//            tilemin <= rowmin + 6e-4 gets the row appended to its list.
//            Then one pass per tile: stage the tile's 128 codebook rows in
//            LDS (per-K-chunk), sweep its row list, recompute the EXACT fp32
//            chain (k-ascending fmaf, epilogue t = A_n + ce_j;
//            d = fmaf(-2,acc,t)) == R2 bits; packed-key atomicMin combines
//            across tiles with lowest-index tie-break.  Margin 6e-4 >
//            2*eps + 2*ulp covers winner + all exact grid ties.
// ---------------------------------------------------------------------------

#define N_E     8192
#define C_DIM   256
#define N_VEC   16384            // 16*32*32
#define N_ELEM  4194304          // 16*256*32*32
#define MARGIN  6.0e-4f

// ws layout (bytes)
#define WS_COUNTS   0            // int[8192]                 32768
#define WS_M        32768        // float[65536]              262144
#define WS_ACCUM    294912       // double[2]                 16
#define WS_RN       294928       // float[8192]               32768
#define WS_CE       327696       // float[8192]               32768
#define WS_A        360464       // float[16384]              65536
#define WS_IDXI     426000       // int[16384]                65536
#define WS_KEYS     491536       // u64[16384]                131072
#define WS_LISTLEN  622608       // int[64]                   256
#define WS_LISTS    622864       // int[64*16384]             4194304
#define WS_TILEMIN  4817168      // float[64*16384] [t][n]    4194304
#define WS_ZT       9011472      // float[16384*256]          16777216
#define WS_ZBF      25788688     // ushort[16384*256]         8388608
#define WS_CBBF     34177296     // ushort[8192*256]          4194304
#define WS_ZERO_BYTES 294928     // counts + M + accum

typedef short short8v __attribute__((ext_vector_type(8)));
typedef float f32x4  __attribute__((ext_vector_type(4)));

__device__ inline unsigned short f2bf(float f) {       // RNE fp32->bf16 (no NaN in data)
    unsigned int x = __float_as_uint(f);
    return (unsigned short)((x + 0x7fffu + ((x >> 16) & 1u)) >> 16);
}

// ---------------------------------------------------------------------------
// codebook row squared norms + reciprocal norms (unchanged bits vs R2..R4)
__global__ __launch_bounds__(256) void k_sqnorm(const float* __restrict__ cb,
                                                float* __restrict__ ce,
                                                float* __restrict__ rn) {
    int j = blockIdx.x;
    int tid = threadIdx.x;
    float v = cb[(size_t)j * C_DIM + tid];
    float s = v * v;
    #pragma unroll
    for (int off = 32; off > 0; off >>= 1) s += __shfl_down(s, off, 64);
    __shared__ float sh[4];
    if ((tid & 63) == 0) sh[tid >> 6] = s;
    __syncthreads();
    if (tid == 0) {
        float t = sh[0] + sh[1] + sh[2] + sh[3];
        ce[j] = t;
        rn[j] = 1.0f / sqrtf(t);
    }
}

// ---------------------------------------------------------------------------
// z row squared norms (unchanged bits vs R2..R4)
__global__ __launch_bounds__(256) void k_znorm(const float* __restrict__ z,
                                               float* __restrict__ A) {
    int n = blockIdx.x * 256 + threadIdx.x;      // n = b*1024 + hw
    int b = n >> 10, hw = n & 1023;
    const float* zp = z + (size_t)b * 262144 + hw;
    float a = 0.0f;
    #pragma unroll 8
    for (int c = 0; c < C_DIM; ++c) {
        float v = zp[(size_t)c * 1024];
        a = fmaf(v, v, a);
    }
    A[n] = a;
}

// ---------------------------------------------------------------------------
// transpose z -> zT (fp32, [n][k]) and zbf (bf16 bits, [n][k])
__global__ __launch_bounds__(256) void k_transpose(const float* __restrict__ z,
                                                   float* __restrict__ zT,
                                                   unsigned short* __restrict__ zbf) {
    int n = blockIdx.x * 256 + threadIdx.x;
    int b = n >> 10, hw = n & 1023;
    int c0 = blockIdx.y * 64;
    const float* zp = z + (size_t)b * 262144 + hw;
    #pragma unroll 8
    for (int c = c0; c < c0 + 64; ++c) {
        float v = zp[(size_t)c * 1024];
        zT[(size_t)n * C_DIM + c] = v;
        zbf[(size_t)n * C_DIM + c] = f2bf(v);
    }
}

// ---------------------------------------------------------------------------
// codebook fp32 -> bf16 bits
__global__ __launch_bounds__(256) void k_cvtcb(const float* __restrict__ cb,
                                               unsigned short* __restrict__ cbbf) {
    size_t i = ((size_t)blockIdx.x * 256 + threadIdx.x) * 4;
    float4 v = *(const float4*)&cb[i];
    ushort4 u = { f2bf(v.x), f2bf(v.y), f2bf(v.z), f2bf(v.w) };
    *(ushort4*)&cbbf[i] = u;
}

// ---------------------------------------------------------------------------
// Stage A: bf16 MFMA GEMM, 128n x 128j per block (4 waves, 2x2), K=256.
// Epilogue: tilemin[bx][n] = -2 * max_j dot_approx   (transposed layout)
__global__ __launch_bounds__(256) void k_mfma(const unsigned short* __restrict__ zbf,
                                              const unsigned short* __restrict__ cbbf,
                                              float* __restrict__ tilemin) {
    __shared__ unsigned short As[128 * 72];   // [n][k], pad 72 -> 2-way max
    __shared__ unsigned short Bs[128 * 72];   // [j][k]
    __shared__ float smin[128][2];

    const int tid = threadIdx.x;
    const int bx = blockIdx.x, by = blockIdx.y;
    const int n0 = by * 128, j0 = bx * 128;
    const int wave = tid >> 6, lane = tid & 63;
    const int wx = wave & 1, wy = wave >> 1;      // wave tile: 64n x 64j
    const int g = lane >> 4, c = lane & 15;
    const int kg = tid & 7, nl = tid >> 3;        // staging: 8 k-groups x 32 rows

    f32x4 acc[4][4];
    #pragma unroll
    for (int i = 0; i < 4; ++i)
        #pragma unroll
        for (int j = 0; j < 4; ++j) acc[i][j] = (f32x4){0.f, 0.f, 0.f, 0.f};

    for (int kc = 0; kc < C_DIM; kc += 64) {
        __syncthreads();
        #pragma unroll
        for (int p = 0; p < 4; ++p) {
            int row = nl + 32 * p;
            *(short8v*)&As[row * 72 + kg * 8] =
                *(const short8v*)&zbf[(size_t)(n0 + row) * C_DIM + kc + kg * 8];
            *(short8v*)&Bs[row * 72 + kg * 8] =
                *(const short8v*)&cbbf[(size_t)(j0 + row) * C_DIM + kc + kg * 8];
        }
        __syncthreads();

        #pragma unroll
        for (int kk = 0; kk < 64; kk += 32) {
            short8v a[4], b[4];
            #pragma unroll
            for (int f = 0; f < 4; ++f)
                a[f] = *(const short8v*)&As[(wy * 64 + f * 16 + c) * 72 + kk + g * 8];
            #pragma unroll
            for (int f = 0; f < 4; ++f)
                b[f] = *(const short8v*)&Bs[(wx * 64 + f * 16 + c) * 72 + kk + g * 8];
            #pragma unroll
            for (int nf = 0; nf < 4; ++nf)
                #pragma unroll
                for (int jf = 0; jf < 4; ++jf)
                    acc[nf][jf] = __builtin_amdgcn_mfma_f32_16x16x32_bf16(
                        a[nf], b[jf], acc[nf][jf], 0, 0, 0);
        }
    }

    // C layout: col = lane&15 (j), row = (lane>>4)*4 + reg (n).  max over j.
    #pragma unroll
    for (int nf = 0; nf < 4; ++nf) {
        #pragma unroll
        for (int r = 0; r < 4; ++r) {
            float mx = acc[nf][0][r];
            #pragma unroll
            for (int jf = 1; jf < 4; ++jf) mx = fmaxf(mx, acc[nf][jf][r]);
            #pragma unroll
            for (int off = 1; off < 16; off <<= 1)
                mx = fmaxf(mx, __shfl_xor(mx, off, 64));
            if (c == 0) smin[wy * 64 + nf * 16 + g * 4 + r][wx] = -2.0f * mx;
        }
    }
    __syncthreads();
    if (tid < 128)
        tilemin[(size_t)bx * N_VEC + n0 + tid] = fminf(smin[tid][0], smin[tid][1]);
}

// ---------------------------------------------------------------------------
// Stage B1: per row rowmin + margin -> append row to each qualifying tile list
__global__ __launch_bounds__(256) void k_cand(const float* __restrict__ tilemin,
                                              int* __restrict__ listlen,
                                              int* __restrict__ lists) {
    int n = blockIdx.x * 256 + threadIdx.x;
    float rm = 3.4e38f;
    for (int t = 0; t < 64; ++t)                          // coalesced: [t][n]
        rm = fminf(rm, tilemin[(size_t)t * N_VEC + n]);
    float thr = rm + MARGIN;
    for (int t = 0; t < 64; ++t) {
        if (tilemin[(size_t)t * N_VEC + n] <= thr) {
            int p = atomicAdd(&listlen[t], 1);
            lists[t * N_VEC + p] = n;
        }
    }
}

// ---------------------------------------------------------------------------
// Stage B2: tile-centric exact refine.  grid (64 tiles, 128).  Block (t,y)
// processes row-batches y, y+128, ... (32 rows each) of tile t's list; stages
// the tile's codebook rows in LDS per 64-K chunk.  Exact R2 fp32 chain.
// thread: jg = tid&31, rg = tid>>5;  j = jg + 32*jj (jj<4);  row = rg*4+rr.
__global__ __launch_bounds__(256) void k_refine2(const float* __restrict__ zT,
                                                 const float* __restrict__ cb,
                                                 const float* __restrict__ ce,
                                                 const float* __restrict__ A,
                                                 const int* __restrict__ listlen,
                                                 const int* __restrict__ lists,
                                                 unsigned long long* __restrict__ keys) {
    __shared__ float e_s[128 * 68];
    __shared__ float z_s[32 * 68];
    __shared__ int   rows_s[32];

    const int t = blockIdx.x;
    const int len = listlen[t];
    const int tid = threadIdx.x;
    const int jg = tid & 31, rg = tid >> 5;
    const int j0 = t * 128;

    for (int b0 = blockIdx.y * 32; b0 < len; b0 += 128 * 32) {
        const int nrows = min(32, len - b0);
        __syncthreads();                           // protect prev batch's LDS
        if (tid < 32)
            rows_s[tid] = lists[t * N_VEC + b0 + min(tid, nrows - 1)];  // pad dup row0

        float acc[4][4];
        #pragma unroll
        for (int rr = 0; rr < 4; ++rr)
            #pragma unroll
            for (int jj = 0; jj < 4; ++jj) acc[rr][jj] = 0.0f;

        for (int kc = 0; kc < C_DIM; kc += 64) {
            __syncthreads();
            {   // stage e chunk: 128 j x 64 k
                int jr = tid >> 1, ko = (tid & 1) * 32;
                #pragma unroll
                for (int i = 0; i < 8; ++i)
                    *(float4*)&e_s[jr * 68 + ko + i * 4] =
                        *(const float4*)&cb[(size_t)(j0 + jr) * C_DIM + kc + ko + i * 4];
            }
            {   // stage z chunk: 32 rows x 64 k
                int r = tid >> 3, ko = (tid & 7) * 8;
                const float* zp = &zT[(size_t)rows_s[r] * C_DIM + kc + ko];
                *(float4*)&z_s[r * 68 + ko]     = *(const float4*)&zp[0];
                *(float4*)&z_s[r * 68 + ko + 4] = *(const float4*)&zp[4];
            }
            __syncthreads();

            #pragma unroll
            for (int k4 = 0; k4 < 16; ++k4) {
                float4 ef[4], zf[4];
                #pragma unroll
                for (int jj = 0; jj < 4; ++jj)
                    ef[jj] = *(const float4*)&e_s[(jg + 32 * jj) * 68 + k4 * 4];
                #pragma unroll
                for (int rr = 0; rr < 4; ++rr)
                    zf[rr] = *(const float4*)&z_s[(rg * 4 + rr) * 68 + k4 * 4];
                #pragma unroll
                for (int kk = 0; kk < 4; ++kk)       // k ascending: exact chain
                    #pragma unroll
                    for (int rr = 0; rr < 4; ++rr)
                        #pragma unroll
                        for (int jj = 0; jj < 4; ++jj)
                            acc[rr][jj] = fmaf(((const float*)&zf[rr])[kk],
                                               ((const float*)&ef[jj])[kk], acc[rr][jj]);
            }
        }

        // epilogue: exact d, packed key, min over jj then over jg lanes
        #pragma unroll
        for (int rr = 0; rr < 4; ++rr) {
            const int n = rows_s[rg * 4 + rr];
            const float An = A[n];
            unsigned long long best = ~0ull;
            #pragma unroll
            for (int jj = 0; jj < 4; ++jj) {
                int j = j0 + jg + 32 * jj;
                float tt = An + ce[j];
                float d = fmaf(-2.0f, acc[rr][jj], tt);   // == R2 epilogue bits
                unsigned int sd = __float_as_uint(d);
                sd = (sd & 0x80000000u) ? ~sd : (sd | 0x80000000u);
                unsigned long long key = ((unsigned long long)sd << 32) | (unsigned)j;
                best = key < best ? key : best;
            }
            #pragma unroll
            for (int off = 16; off > 0; off >>= 1) {      // reduce 32 jg lanes
                unsigned long long o = __shfl_xor(best, off, 64);
                best = o < best ? o : best;
            }
            if (jg == 0) atomicMin(&keys[n], best);
        }
    }
}

// ---------------------------------------------------------------------------
// unpack keys -> idx (int + float out), histogram counts
__global__ __launch_bounds__(256) void k_combine(const unsigned long long* __restrict__ keys,
                                                 int* __restrict__ idxi,
                                                 float* __restrict__ out_idx,
                                                 int* __restrict__ counts) {
    int n = blockIdx.x * 256 + threadIdx.x;
    unsigned long long k = keys[n];
    int idx = (int)(k & 0xFFFFFFFFull);
    idxi[n] = idx;
    out_idx[n] = (float)idx;
    atomicAdd(&counts[idx], 1);
}

// ---------------------------------------------------------------------------
// gather z_q (write in (B,C,H,W) layout) + fp64 SSE reduction for the loss
__global__ __launch_bounds__(256) void k_gather(const float* __restrict__ z,
                                                const float* __restrict__ cb,
                                                const int* __restrict__ idxi,
                                                float* __restrict__ out,
                                                double* __restrict__ sse) {
    int bh = blockIdx.x;                 // b*32 + h
    int b = bh >> 5, h = bh & 31;
    int tid = threadIdx.x;
    int w = tid & 31, cy = tid >> 5;
    int n = b * 1024 + h * 32 + w;
    int jid = idxi[n];
    const float* cbr = cb + (size_t)jid * C_DIM;
    size_t zb = (size_t)b * 262144 + h * 32 + w;

    double acc = 0.0;
    #pragma unroll 4
    for (int cc = 0; cc < 32; ++cc) {
        int c = cc * 8 + cy;
        float e = cbr[c];
        size_t zi = zb + (size_t)c * 1024;
        float d = e - z[zi];
        out[zi] = e;
        acc += (double)(d * d);
    }
    #pragma unroll
    for (int off = 32; off > 0; off >>= 1) acc += __shfl_down(acc, off, 64);
    __shared__ double sh[4];
    if ((tid & 63) == 0) sh[tid >> 6] = acc;
    __syncthreads();
    if (tid == 0) atomicAdd(sse, sh[0] + sh[1] + sh[2] + sh[3]);
}

// ---------------------------------------------------------------------------
// Gram matrix M = Wn^T Wn  (256x256), j-split with float atomics
__global__ __launch_bounds__(256) void k_gram(const float* __restrict__ cb,
                                              const float* __restrict__ rn,
                                              float* __restrict__ M) {
    __shared__ float aT[64][68];
    __shared__ float bT[64][68];
    int k0 = blockIdx.x * 64, l0 = blockIdx.y * 64;
    int jc0 = blockIdx.z * 256;
    int tid = threadIdx.x;
    int tk = tid & 15, tl = tid >> 4;
    float acc[4][4];
    #pragma unroll
    for (int i = 0; i < 4; ++i)
        #pragma unroll
        for (int l = 0; l < 4; ++l) acc[i][l] = 0.0f;

    for (int jc = jc0; jc < jc0 + 256; jc += 64) {
        __syncthreads();
        {
            int kk = tid & 63, jj0 = tid >> 6;
            #pragma unroll
            for (int p = 0; p < 16; ++p) {
                int jj = p * 4 + jj0;
                float r = rn[jc + jj];
                const float* row = cb + (size_t)(jc + jj) * C_DIM;
                aT[jj][kk] = row[k0 + kk] * r;
                bT[jj][kk] = row[l0 + kk] * r;
            }
        }
        __syncthreads();
        #pragma unroll 8
        for (int jj = 0; jj < 64; ++jj) {
            float4 av = *(const float4*)&aT[jj][tk * 4];
            float4 bv = *(const float4*)&bT[jj][tl * 4];
            float a4[4] = {av.x, av.y, av.z, av.w};
            float b4[4] = {bv.x, bv.y, bv.z, bv.w};
            #pragma unroll
            for (int i = 0; i < 4; ++i)
                #pragma unroll
                for (int l = 0; l < 4; ++l)
                    acc[i][l] = fmaf(a4[i], b4[l], acc[i][l]);
        }
    }
    #pragma unroll
    for (int i = 0; i < 4; ++i)
        #pragma unroll
        for (int l = 0; l < 4; ++l)
            atomicAdd(&M[(size_t)(k0 + tk * 4 + i) * C_DIM + l0 + tl * 4 + l], acc[i][l]);
}

// ---------------------------------------------------------------------------
// finalize scalars: loss, ortho = (||M||_F^2 - n_e)/n_e^2, perplexity
__global__ __launch_bounds__(256) void k_final(const float* __restrict__ M,
                                               const int* __restrict__ counts,
                                               const double* __restrict__ accum,
                                               float* __restrict__ out_scalars) {
    int tid = threadIdx.x;
    __shared__ double sh[4];

    double s = 0.0;
    for (int i = tid; i < C_DIM * C_DIM; i += 256) {
        double m = M[i];
        s += m * m;
    }
    #pragma unroll
    for (int off = 32; off > 0; off >>= 1) s += __shfl_down(s, off, 64);
    if ((tid & 63) == 0) sh[tid >> 6] = s;
    __syncthreads();
    double S = sh[0] + sh[1] + sh[2] + sh[3];
    __syncthreads();

    double H = 0.0;
    for (int j = tid; j < N_E; j += 256) {
        double p = counts[j] * (1.0 / (double)N_VEC);
        H += p * log(p + 1e-10);
    }
    #pragma unroll
    for (int off = 32; off > 0; off >>= 1) H += __shfl_down(H, off, 64);
    if ((tid & 63) == 0) sh[tid >> 6] = H;
    __syncthreads();

    if (tid == 0) {
        double Hs = sh[0] + sh[1] + sh[2] + sh[3];
        out_scalars[0] = (float)(1.25 * accum[0] / (double)N_ELEM);        // loss
        out_scalars[1] = (float)((S - (double)N_E) / ((double)N_E * N_E)); // ortho
        out_scalars[2] = (float)exp(-Hs);                                  // perplexity
    }
}

// ---------------------------------------------------------------------------
extern "C" void kernel_launch(void* const* d_in, const int* in_sizes, int n_in,
                              void* d_out, int out_size, void* d_ws, size_t ws_size,
                              hipStream_t stream) {
    (void)in_sizes; (void)n_in; (void)out_size; (void)ws_size;
    const float* z  = (const float*)d_in[0];
    const float* cb = (const float*)d_in[1];
    float* out = (float*)d_out;

    char* ws = (char*)d_ws;
    int* counts            = (int*)(ws + WS_COUNTS);
    float* M               = (float*)(ws + WS_M);
    double* accum          = (double*)(ws + WS_ACCUM);
    float* rn              = (float*)(ws + WS_RN);
    float* ce              = (float*)(ws + WS_CE);
    float* A               = (float*)(ws + WS_A);
    int* idxi              = (int*)(ws + WS_IDXI);
    unsigned long long* keys = (unsigned long long*)(ws + WS_KEYS);
    int* listlen           = (int*)(ws + WS_LISTLEN);
    int* lists             = (int*)(ws + WS_LISTS);
    float* tilemin         = (float*)(ws + WS_TILEMIN);
    float* zT              = (float*)(ws + WS_ZT);
    unsigned short* zbf    = (unsigned short*)(ws + WS_ZBF);
    unsigned short* cbbf   = (unsigned short*)(ws + WS_CBBF);

    float* out_scalars = out + N_ELEM;       // loss, ortho, perplexity
    float* out_idx     = out + N_ELEM + 3;   // 16384 idx as float

    hipMemsetAsync(ws, 0, WS_ZERO_BYTES, stream);                 // counts+M+accum
    hipMemsetAsync(ws + WS_KEYS, 0xFF, 131072, stream);           // keys
    hipMemsetAsync(ws + WS_LISTLEN, 0, 256, stream);              // listlen

    k_sqnorm<<<N_E, 256, 0, stream>>>(cb, ce, rn);
    k_znorm<<<N_VEC / 256, 256, 0, stream>>>(z, A);
    k_transpose<<<dim3(N_VEC / 256, 4), 256, 0, stream>>>(z, zT, zbf);
    k_cvtcb<<<(N_E * C_DIM) / (256 * 4), 256, 0, stream>>>(cb, cbbf);
    k_mfma<<<dim3(N_E / 128, N_VEC / 128), 256, 0, stream>>>(zbf, cbbf, tilemin);
    k_cand<<<N_VEC / 256, 256, 0, stream>>>(tilemin, listlen, lists);
    k_refine2<<<dim3(64, 128), 256, 0, stream>>>(zT, cb, ce, A, listlen, lists, keys);
    k_combine<<<N_VEC / 256, 256, 0, stream>>>(keys, idxi, out_idx, counts);
    k_gather<<<512, 256, 0, stream>>>(z, cb, idxi, out, accum);
    k_gram<<<dim3(4, 4, 32), 256, 0, stream>>>(cb, rn, M);
    k_final<<<1, 256, 0, stream>>>(M, counts, accum, out_scalars);
}

// Round 6
// 494.425 us; speedup vs baseline: 2.1121x; 1.1368x over previous
//
#include <hip/hip_runtime.h>
#include <hip/hip_bf16.h>
#include <math.h>

// ---------------------------------------------------------------------------
// VQ quantizer:
//   in[0] = z        (16,256,32,32) fp32   -> N=16384 vectors of C=256
//   in[1] = codebook (8192,256)     fp32
//   out   = [ z_q (B,C,H,W) 4194304 | loss | ortho | perplexity | idx(16384) as float ]
//
// idx strategy (two-stage, bit-matching the R2..R5 passing semantics):
//   Stage A: bf16 MFMA GEMM; tilemin[t][n] = -2*max_j dot_approx (err<=1.54e-4)
//   Stage B: rows whose tilemin is within MARGIN of rowmin get the EXACT fp32
//            chain recomputed tile-centrically (LDS-staged codebook tile);
//            d = fmaf(-2,acc, A_n + ce_j) == R2 bits; packed-key atomicMin
//            keeps global min with lowest-index tie-break (order-independent).
// ---------------------------------------------------------------------------

#define N_E     8192
#define C_DIM   256
#define N_VEC   16384            // 16*32*32
#define N_ELEM  4194304          // 16*256*32*32
#define MARGIN  6.0e-4f

// ws layout (bytes)
#define WS_COUNTS   0            // int[8192]                 32768
#define WS_M        32768        // float[65536]              262144
#define WS_ACCUM    294912       // double[2]                 16
#define WS_RN       294928       // float[8192]               32768
#define WS_CE       327696       // float[8192]               32768
#define WS_A        360464       // float[16384]              65536
#define WS_IDXI     426000       // int[16384]                65536
#define WS_KEYS     491536       // u64[16384]                131072
#define WS_LISTLEN  622608       // int[64]                   256
#define WS_LISTS    622864       // int[64*16384]             4194304
#define WS_TILEMIN  4817168      // float[64*16384] [t][n]    4194304
#define WS_ZT       9011472      // float[16384*256]          16777216
#define WS_ZBF      25788688     // ushort[16384*256]         8388608
#define WS_CBBF     34177296     // ushort[8192*256]          4194304
#define WS_THR      38371600     // float[16384]              65536
#define WS_ZERO_BYTES 294928     // counts + M + accum

typedef short short8v __attribute__((ext_vector_type(8)));
typedef float f32x4  __attribute__((ext_vector_type(4)));

__device__ inline unsigned short f2bf(float f) {       // RNE fp32->bf16 (no NaN in data)
    unsigned int x = __float_as_uint(f);
    return (unsigned short)((x + 0x7fffu + ((x >> 16) & 1u)) >> 16);
}

// ---------------------------------------------------------------------------
// codebook row squared norms + reciprocal norms (unchanged bits vs R2..R5)
__global__ __launch_bounds__(256) void k_sqnorm(const float* __restrict__ cb,
                                                float* __restrict__ ce,
                                                float* __restrict__ rn) {
    int j = blockIdx.x;
    int tid = threadIdx.x;
    float v = cb[(size_t)j * C_DIM + tid];
    float s = v * v;
    #pragma unroll
    for (int off = 32; off > 0; off >>= 1) s += __shfl_down(s, off, 64);
    __shared__ float sh[4];
    if ((tid & 63) == 0) sh[tid >> 6] = s;
    __syncthreads();
    if (tid == 0) {
        float t = sh[0] + sh[1] + sh[2] + sh[3];
        ce[j] = t;
        rn[j] = 1.0f / sqrtf(t);
    }
}

// ---------------------------------------------------------------------------
// z row squared norms (unchanged bits vs R2..R5)
__global__ __launch_bounds__(256) void k_znorm(const float* __restrict__ z,
                                               float* __restrict__ A) {
    int n = blockIdx.x * 256 + threadIdx.x;      // n = b*1024 + hw
    int b = n >> 10, hw = n & 1023;
    const float* zp = z + (size_t)b * 262144 + hw;
    float a = 0.0f;
    #pragma unroll 8
    for (int c = 0; c < C_DIM; ++c) {
        float v = zp[(size_t)c * 1024];
        a = fmaf(v, v, a);
    }
    A[n] = a;
}

// ---------------------------------------------------------------------------
// transpose z -> zT (fp32, [n][k]) and zbf (bf16 bits, [n][k])
__global__ __launch_bounds__(256) void k_transpose(const float* __restrict__ z,
                                                   float* __restrict__ zT,
                                                   unsigned short* __restrict__ zbf) {
    int n = blockIdx.x * 256 + threadIdx.x;
    int b = n >> 10, hw = n & 1023;
    int c0 = blockIdx.y * 64;
    const float* zp = z + (size_t)b * 262144 + hw;
    #pragma unroll 8
    for (int c = c0; c < c0 + 64; ++c) {
        float v = zp[(size_t)c * 1024];
        zT[(size_t)n * C_DIM + c] = v;
        zbf[(size_t)n * C_DIM + c] = f2bf(v);
    }
}

// ---------------------------------------------------------------------------
// codebook fp32 -> bf16 bits
__global__ __launch_bounds__(256) void k_cvtcb(const float* __restrict__ cb,
                                               unsigned short* __restrict__ cbbf) {
    size_t i = ((size_t)blockIdx.x * 256 + threadIdx.x) * 4;
    float4 v = *(const float4*)&cb[i];
    ushort4 u = { f2bf(v.x), f2bf(v.y), f2bf(v.z), f2bf(v.w) };
    *(ushort4*)&cbbf[i] = u;
}

// ---------------------------------------------------------------------------
// Stage A: bf16 MFMA GEMM, 128n x 128j per block (4 waves, 2x2), K=256.
// XCD-swizzled block remap: each XCD gets 16 contiguous n-panels (1 MB of zbf)
// + the full 4 MB cbbf ~= L2-resident, instead of the full 12 MB working set.
// Epilogue: tilemin[bx][n] = -2 * max_j dot_approx   (transposed layout)
__global__ __launch_bounds__(256) void k_mfma(const unsigned short* __restrict__ zbf,
                                              const unsigned short* __restrict__ cbbf,
                                              float* __restrict__ tilemin) {
    __shared__ unsigned short As[128 * 72];   // [n][k], pad 72 -> 2-way (free)
    __shared__ unsigned short Bs[128 * 72];   // [j][k]
    __shared__ float smin[128][2];

    const int tid = threadIdx.x;
    const int lin = blockIdx.y * 64 + blockIdx.x;         // 8192 blocks
    const int swz = (lin & 7) * 1024 + (lin >> 3);        // bijective XCD chunking
    const int bx = swz & 63, by = swz >> 6;
    const int n0 = by * 128, j0 = bx * 128;
    const int wave = tid >> 6, lane = tid & 63;
    const int wx = wave & 1, wy = wave >> 1;      // wave tile: 64n x 64j
    const int g = lane >> 4, c = lane & 15;
    const int kg = tid & 7, nl = tid >> 3;        // staging: 8 k-groups x 32 rows

    f32x4 acc[4][4];
    #pragma unroll
    for (int i = 0; i < 4; ++i)
        #pragma unroll
        for (int j = 0; j < 4; ++j) acc[i][j] = (f32x4){0.f, 0.f, 0.f, 0.f};

    for (int kc = 0; kc < C_DIM; kc += 64) {
        __syncthreads();
        #pragma unroll
        for (int p = 0; p < 4; ++p) {
            int row = nl + 32 * p;
            *(short8v*)&As[row * 72 + kg * 8] =
                *(const short8v*)&zbf[(size_t)(n0 + row) * C_DIM + kc + kg * 8];
            *(short8v*)&Bs[row * 72 + kg * 8] =
                *(const short8v*)&cbbf[(size_t)(j0 + row) * C_DIM + kc + kg * 8];
        }
        __syncthreads();

        #pragma unroll
        for (int kk = 0; kk < 64; kk += 32) {
            short8v a[4], b[4];
            #pragma unroll
            for (int f = 0; f < 4; ++f)
                a[f] = *(const short8v*)&As[(wy * 64 + f * 16 + c) * 72 + kk + g * 8];
            #pragma unroll
            for (int f = 0; f < 4; ++f)
                b[f] = *(const short8v*)&Bs[(wx * 64 + f * 16 + c) * 72 + kk + g * 8];
            #pragma unroll
            for (int nf = 0; nf < 4; ++nf)
                #pragma unroll
                for (int jf = 0; jf < 4; ++jf)
                    acc[nf][jf] = __builtin_amdgcn_mfma_f32_16x16x32_bf16(
                        a[nf], b[jf], acc[nf][jf], 0, 0, 0);
        }
    }

    // C layout: col = lane&15 (j), row = (lane>>4)*4 + reg (n).  max over j.
    #pragma unroll
    for (int nf = 0; nf < 4; ++nf) {
        #pragma unroll
        for (int r = 0; r < 4; ++r) {
            float mx = acc[nf][0][r];
            #pragma unroll
            for (int jf = 1; jf < 4; ++jf) mx = fmaxf(mx, acc[nf][jf][r]);
            #pragma unroll
            for (int off = 1; off < 16; off <<= 1)
                mx = fmaxf(mx, __shfl_xor(mx, off, 64));
            if (c == 0) smin[wy * 64 + nf * 16 + g * 4 + r][wx] = -2.0f * mx;
        }
    }
    __syncthreads();
    if (tid < 128)
        tilemin[(size_t)bx * N_VEC + n0 + tid] = fminf(smin[tid][0], smin[tid][1]);
}

// ---------------------------------------------------------------------------
// Stage B1a: thr[n] = min_t tilemin[t][n] + MARGIN.   256 blocks, 4-way
// t-parallel per n, LDS reduce.  All loads 256B-contiguous per 64-lane group.
__global__ __launch_bounds__(256) void k_rowmin(const float* __restrict__ tilemin,
                                                float* __restrict__ thr) {
    __shared__ float red[4][64];
    const int nl = threadIdx.x & 63, tg = threadIdx.x >> 6;
    const int n = blockIdx.x * 64 + nl;
    float m = 3.4e38f;
    #pragma unroll
    for (int i = 0; i < 16; ++i)
        m = fminf(m, tilemin[(size_t)(tg * 16 + i) * N_VEC + n]);
    red[tg][nl] = m;
    __syncthreads();
    if (tg == 0)
        thr[n] = fminf(fminf(red[0][nl], red[1][nl]),
                       fminf(red[2][nl], red[3][nl])) + MARGIN;
}

// ---------------------------------------------------------------------------
// Stage B1b: build per-tile candidate lists.  grid (64 tiles, 8 n-chunks).
// Wave-aggregated compaction: one atomicAdd per non-empty wave-ballot.
// List order is arbitrary -- k_refine2's keyed atomicMin is order-independent.
__global__ __launch_bounds__(256) void k_build(const float* __restrict__ tilemin,
                                               const float* __restrict__ thr,
                                               int* __restrict__ listlen,
                                               int* __restrict__ lists) {
    const int t = blockIdx.x;
    const int lane = threadIdx.x & 63;
    #pragma unroll
    for (int it = 0; it < 8; ++it) {
        int n = blockIdx.y * 2048 + it * 256 + threadIdx.x;
        bool q = tilemin[(size_t)t * N_VEC + n] <= thr[n];
        unsigned long long mask = __ballot(q);
        if (mask) {
            int ldr = __ffsll(mask) - 1;
            int base = 0;
            if (lane == ldr) base = atomicAdd(&listlen[t], __popcll(mask));
            base = __shfl(base, ldr, 64);
            if (q) {
                int pre = __popcll(mask & ((1ull << lane) - 1ull));
                lists[t * N_VEC + base + pre] = n;
            }
        }
    }
}

// ---------------------------------------------------------------------------
// Stage B2: tile-centric exact refine (unchanged vs R5).  grid (64, 128).
__global__ __launch_bounds__(256) void k_refine2(const float* __restrict__ zT,
                                                 const float* __restrict__ cb,
                                                 const float* __restrict__ ce,
                                                 const float* __restrict__ A,
                                                 const int* __restrict__ listlen,
                                                 const int* __restrict__ lists,
                                                 unsigned long long* __restrict__ keys) {
    __shared__ float e_s[128 * 68];
    __shared__ float z_s[32 * 68];
    __shared__ int   rows_s[32];

    const int t = blockIdx.x;
    const int len = listlen[t];
    const int tid = threadIdx.x;
    const int jg = tid & 31, rg = tid >> 5;
    const int j0 = t * 128;

    for (int b0 = blockIdx.y * 32; b0 < len; b0 += 128 * 32) {
        const int nrows = min(32, len - b0);
        __syncthreads();                           // protect prev batch's LDS
        if (tid < 32)
            rows_s[tid] = lists[t * N_VEC + b0 + min(tid, nrows - 1)];  // pad dup row0

        float acc[4][4];
        #pragma unroll
        for (int rr = 0; rr < 4; ++rr)
            #pragma unroll
            for (int jj = 0; jj < 4; ++jj) acc[rr][jj] = 0.0f;

        for (int kc = 0; kc < C_DIM; kc += 64) {
            __syncthreads();
            {   // stage e chunk: 128 j x 64 k
                int jr = tid >> 1, ko = (tid & 1) * 32;
                #pragma unroll
                for (int i = 0; i < 8; ++i)
                    *(float4*)&e_s[jr * 68 + ko + i * 4] =
                        *(const float4*)&cb[(size_t)(j0 + jr) * C_DIM + kc + ko + i * 4];
            }
            {   // stage z chunk: 32 rows x 64 k
                int r = tid >> 3, ko = (tid & 7) * 8;
                const float* zp = &zT[(size_t)rows_s[r] * C_DIM + kc + ko];
                *(float4*)&z_s[r * 68 + ko]     = *(const float4*)&zp[0];
                *(float4*)&z_s[r * 68 + ko + 4] = *(const float4*)&zp[4];
            }
            __syncthreads();

            #pragma unroll
            for (int k4 = 0; k4 < 16; ++k4) {
                float4 ef[4], zf[4];
                #pragma unroll
                for (int jj = 0; jj < 4; ++jj)
                    ef[jj] = *(const float4*)&e_s[(jg + 32 * jj) * 68 + k4 * 4];
                #pragma unroll
                for (int rr = 0; rr < 4; ++rr)
                    zf[rr] = *(const float4*)&z_s[(rg * 4 + rr) * 68 + k4 * 4];
                #pragma unroll
                for (int kk = 0; kk < 4; ++kk)       // k ascending: exact chain
                    #pragma unroll
                    for (int rr = 0; rr < 4; ++rr)
                        #pragma unroll
                        for (int jj = 0; jj < 4; ++jj)
                            acc[rr][jj] = fmaf(((const float*)&zf[rr])[kk],
                                               ((const float*)&ef[jj])[kk], acc[rr][jj]);
            }
        }

        // epilogue: exact d, packed key, min over jj then over jg lanes
        #pragma unroll
        for (int rr = 0; rr < 4; ++rr) {
            const int n = rows_s[rg * 4 + rr];
            const float An = A[n];
            unsigned long long best = ~0ull;
            #pragma unroll
            for (int jj = 0; jj < 4; ++jj) {
                int j = j0 + jg + 32 * jj;
                float tt = An + ce[j];
                float d = fmaf(-2.0f, acc[rr][jj], tt);   // == R2 epilogue bits
                unsigned int sd = __float_as_uint(d);
                sd = (sd & 0x80000000u) ? ~sd : (sd | 0x80000000u);
                unsigned long long key = ((unsigned long long)sd << 32) | (unsigned)j;
                best = key < best ? key : best;
            }
            #pragma unroll
            for (int off = 16; off > 0; off >>= 1) {      // reduce 32 jg lanes
                unsigned long long o = __shfl_xor(best, off, 64);
                best = o < best ? o : best;
            }
            if (jg == 0) atomicMin(&keys[n], best);
        }
    }
}

// ---------------------------------------------------------------------------
// unpack keys -> idx (int + float out), histogram counts
__global__ __launch_bounds__(256) void k_combine(const unsigned long long* __restrict__ keys,
                                                 int* __restrict__ idxi,
                                                 float* __restrict__ out_idx,
                                                 int* __restrict__ counts) {
    int n = blockIdx.x * 256 + threadIdx.x;
    unsigned long long k = keys[n];
    int idx = (int)(k & 0xFFFFFFFFull);
    idxi[n] = idx;
    out_idx[n] = (float)idx;
    atomicAdd(&counts[idx], 1);
}

// ---------------------------------------------------------------------------
// gather z_q (write in (B,C,H,W) layout) + fp64 SSE reduction for the loss
__global__ __launch_bounds__(256) void k_gather(const float* __restrict__ z,
                                                const float* __restrict__ cb,
                                                const int* __restrict__ idxi,
                                                float* __restrict__ out,
                                                double* __restrict__ sse) {
    int bh = blockIdx.x;                 // b*32 + h
    int b = bh >> 5, h = bh & 31;
    int tid = threadIdx.x;
    int w = tid & 31, cy = tid >> 5;
    int n = b * 1024 + h * 32 + w;
    int jid = idxi[n];
    const float* cbr = cb + (size_t)jid * C_DIM;
    size_t zb = (size_t)b * 262144 + h * 32 + w;

    double acc = 0.0;
    #pragma unroll 4
    for (int cc = 0; cc < 32; ++cc) {
        int c = cc * 8 + cy;
        float e = cbr[c];
        size_t zi = zb + (size_t)c * 1024;
        float d = e - z[zi];
        out[zi] = e;
        acc += (double)(d * d);
    }
    #pragma unroll
    for (int off = 32; off > 0; off >>= 1) acc += __shfl_down(acc, off, 64);
    __shared__ double sh[4];
    if ((tid & 63) == 0) sh[tid >> 6] = acc;
    __syncthreads();
    if (tid == 0) atomicAdd(sse, sh[0] + sh[1] + sh[2] + sh[3]);
}

// ---------------------------------------------------------------------------
// Gram matrix M = Wn^T Wn  (256x256), j-split with float atomics
__global__ __launch_bounds__(256) void k_gram(const float* __restrict__ cb,
                                              const float* __restrict__ rn,
                                              float* __restrict__ M) {
    __shared__ float aT[64][68];
    __shared__ float bT[64][68];
    int k0 = blockIdx.x * 64, l0 = blockIdx.y * 64;
    int jc0 = blockIdx.z * 256;
    int tid = threadIdx.x;
    int tk = tid & 15, tl = tid >> 4;
    float acc[4][4];
    #pragma unroll
    for (int i = 0; i < 4; ++i)
        #pragma unroll
        for (int l = 0; l < 4; ++l) acc[i][l] = 0.0f;

    for (int jc = jc0; jc < jc0 + 256; jc += 64) {
        __syncthreads();
        {
            int kk = tid & 63, jj0 = tid >> 6;
            #pragma unroll
            for (int p = 0; p < 16; ++p) {
                int jj = p * 4 + jj0;
                float r = rn[jc + jj];
                const float* row = cb + (size_t)(jc + jj) * C_DIM;
                aT[jj][kk] = row[k0 + kk] * r;
                bT[jj][kk] = row[l0 + kk] * r;
            }
        }
        __syncthreads();
        #pragma unroll 8
        for (int jj = 0; jj < 64; ++jj) {
            float4 av = *(const float4*)&aT[jj][tk * 4];
            float4 bv = *(const float4*)&bT[jj][tl * 4];
            float a4[4] = {av.x, av.y, av.z, av.w};
            float b4[4] = {bv.x, bv.y, bv.z, bv.w};
            #pragma unroll
            for (int i = 0; i < 4; ++i)
                #pragma unroll
                for (int l = 0; l < 4; ++l)
                    acc[i][l] = fmaf(a4[i], b4[l], acc[i][l]);
        }
    }
    #pragma unroll
    for (int i = 0; i < 4; ++i)
        #pragma unroll
        for (int l = 0; l < 4; ++l)
            atomicAdd(&M[(size_t)(k0 + tk * 4 + i) * C_DIM + l0 + tl * 4 + l], acc[i][l]);
}

// ---------------------------------------------------------------------------
// finalize scalars: loss, ortho = (||M||_F^2 - n_e)/n_e^2, perplexity
__global__ __launch_bounds__(256) void k_final(const float* __restrict__ M,
                                               const int* __restrict__ counts,
                                               const double* __restrict__ accum,
                                               float* __restrict__ out_scalars) {
    int tid = threadIdx.x;
    __shared__ double sh[4];

    double s = 0.0;
    for (int i = tid; i < C_DIM * C_DIM; i += 256) {
        double m = M[i];
        s += m * m;
    }
    #pragma unroll
    for (int off = 32; off > 0; off >>= 1) s += __shfl_down(s, off, 64);
    if ((tid & 63) == 0) sh[tid >> 6] = s;
    __syncthreads();
    double S = sh[0] + sh[1] + sh[2] + sh[3];
    __syncthreads();

    double H = 0.0;
    for (int j = tid; j < N_E; j += 256) {
        double p = counts[j] * (1.0 / (double)N_VEC);
        H += p * log(p + 1e-10);
    }
    #pragma unroll
    for (int off = 32; off > 0; off >>= 1) H += __shfl_down(H, off, 64);
    if ((tid & 63) == 0) sh[tid >> 6] = H;
    __syncthreads();

    if (tid == 0) {
        double Hs = sh[0] + sh[1] + sh[2] + sh[3];
        out_scalars[0] = (float)(1.25 * accum[0] / (double)N_ELEM);        // loss
        out_scalars[1] = (float)((S - (double)N_E) / ((double)N_E * N_E)); // ortho
        out_scalars[2] = (float)exp(-Hs);                                  // perplexity
    }
}

// ---------------------------------------------------------------------------
extern "C" void kernel_launch(void* const* d_in, const int* in_sizes, int n_in,
                              void* d_out, int out_size, void* d_ws, size_t ws_size,
                              hipStream_t stream) {
    (void)in_sizes; (void)n_in; (void)out_size; (void)ws_size;
    const float* z  = (const float*)d_in[0];
    const float* cb = (const float*)d_in[1];
    float* out = (float*)d_out;

    char* ws = (char*)d_ws;
    int* counts            = (int*)(ws + WS_COUNTS);
    float* M               = (float*)(ws + WS_M);
    double* accum          = (double*)(ws + WS_ACCUM);
    float* rn              = (float*)(ws + WS_RN);
    float* ce              = (float*)(ws + WS_CE);
    float* A               = (float*)(ws + WS_A);
    int* idxi              = (int*)(ws + WS_IDXI);
    unsigned long long* keys = (unsigned long long*)(ws + WS_KEYS);
    int* listlen           = (int*)(ws + WS_LISTLEN);
    int* lists             = (int*)(ws + WS_LISTS);
    float* tilemin         = (float*)(ws + WS_TILEMIN);
    float* zT              = (float*)(ws + WS_ZT);
    unsigned short* zbf    = (unsigned short*)(ws + WS_ZBF);
    unsigned short* cbbf   = (unsigned short*)(ws + WS_CBBF);
    float* thr             = (float*)(ws + WS_THR);

    float* out_scalars = out + N_ELEM;       // loss, ortho, perplexity
    float* out_idx     = out + N_ELEM + 3;   // 16384 idx as float

    hipMemsetAsync(ws, 0, WS_ZERO_BYTES, stream);                 // counts+M+accum
    hipMemsetAsync(ws + WS_KEYS, 0xFF, 131072, stream);           // keys
    hipMemsetAsync(ws + WS_LISTLEN, 0, 256, stream);              // listlen

    k_sqnorm<<<N_E, 256, 0, stream>>>(cb, ce, rn);
    k_znorm<<<N_VEC / 256, 256, 0, stream>>>(z, A);
    k_transpose<<<dim3(N_VEC / 256, 4), 256, 0, stream>>>(z, zT, zbf);
    k_cvtcb<<<(N_E * C_DIM) / (256 * 4), 256, 0, stream>>>(cb, cbbf);
    k_mfma<<<dim3(N_E / 128, N_VEC / 128), 256, 0, stream>>>(zbf, cbbf, tilemin);
    k_rowmin<<<N_VEC / 64, 256, 0, stream>>>(tilemin, thr);
    k_build<<<dim3(64, 8), 256, 0, stream>>>(tilemin, thr, listlen, lists);
    k_refine2<<<dim3(64, 128), 256, 0, stream>>>(zT, cb, ce, A, listlen, lists, keys);
    k_combine<<<N_VEC / 256, 256, 0, stream>>>(keys, idxi, out_idx, counts);
    k_gather<<<512, 256, 0, stream>>>(z, cb, idxi, out, accum);
    k_gram<<<dim3(4, 4, 32), 256, 0, stream>>>(cb, rn, M);
    k_final<<<1, 256, 0, stream>>>(M, counts, accum, out_scalars);
}

// Round 7
// 438.003 us; speedup vs baseline: 2.3842x; 1.1288x over previous
//
#include <hip/hip_runtime.h>
#include <hip/hip_bf16.h>
#include <math.h>

// ---------------------------------------------------------------------------
// VQ quantizer:
//   in[0] = z        (16,256,32,32) fp32   -> N=16384 vectors of C=256
//   in[1] = codebook (8192,256)     fp32
//   out   = [ z_q (B,C,H,W) 4194304 | loss | ortho | perplexity | idx(16384) as float ]
//
// idx strategy (two-stage, bit-matching the R2..R6 passing semantics):
//   Stage A: bf16 MFMA GEMM; tilemin[t][n] = -2*max_j dot_approx (err<=1.54e-4)
//   Stage B: rows whose tilemin is within MARGIN of rowmin get the EXACT fp32
//            chain recomputed tile-centrically (LDS-staged codebook tile);
//            d = fmaf(-2,acc, A_n + ce_j) == R2 bits; packed-key atomicMin
//            keeps global min with lowest-index tie-break (order-independent).
// ---------------------------------------------------------------------------

#define N_E     8192
#define C_DIM   256
#define N_VEC   16384            // 16*32*32
#define N_ELEM  4194304          // 16*256*32*32
#define MARGIN  6.0e-4f

// ws layout (bytes) -- zero-init fields packed first (single memset)
#define WS_COUNTS   0            // int[8192]                 32768
#define WS_M        32768        // float[65536]              262144
#define WS_ACCUM    294912       // double[2]                 16
#define WS_LISTLEN  294928       // int[64]                   256
#define WS_ZERO_BYTES 295184
#define WS_CE       295184       // float[8192]               32768
#define WS_RN       327952       // float[8192]               32768
#define WS_A        360720       // float[16384]              65536
#define WS_KEYS     426256       // u64[16384]                131072
#define WS_LISTS    557328       // int[64*16384]             4194304
#define WS_TILEMIN  4751632      // float[64*16384] [t][n]    4194304
#define WS_ZBF      8945936      // ushort[16384*256]         8388608
#define WS_CBBF     17334544     // ushort[8192*256]          4194304
#define WS_THR      21528848     // float[16384]              65536

typedef short short8v __attribute__((ext_vector_type(8)));
typedef float f32x4  __attribute__((ext_vector_type(4)));

__device__ inline unsigned short f2bf(float f) {       // RNE fp32->bf16 (no NaN in data)
    unsigned int x = __float_as_uint(f);
    return (unsigned short)((x + 0x7fffu + ((x >> 16) & 1u)) >> 16);
}

// ---------------------------------------------------------------------------
// codebook prep: row sqnorm ce (bits == R2..R6), recip norm rn, bf16 cast
__global__ __launch_bounds__(256) void k_cbprep(const float* __restrict__ cb,
                                                float* __restrict__ ce,
                                                float* __restrict__ rn,
                                                unsigned short* __restrict__ cbbf) {
    int j = blockIdx.x;
    int tid = threadIdx.x;
    float v = cb[(size_t)j * C_DIM + tid];
    cbbf[(size_t)j * C_DIM + tid] = f2bf(v);
    float s = v * v;
    #pragma unroll
    for (int off = 32; off > 0; off >>= 1) s += __shfl_down(s, off, 64);
    __shared__ float sh[4];
    if ((tid & 63) == 0) sh[tid >> 6] = s;
    __syncthreads();
    if (tid == 0) {
        float t = sh[0] + sh[1] + sh[2] + sh[3];
        ce[j] = t;
        rn[j] = 1.0f / sqrtf(t);
    }
}

// ---------------------------------------------------------------------------
// z prep: bf16 transpose chunk write; blockIdx.y==0 additionally computes the
// canonical A[n] chain (verbatim k_znorm body from R2 -> identical bits).
__global__ __launch_bounds__(256) void k_ztrans(const float* __restrict__ z,
                                                unsigned short* __restrict__ zbf,
                                                float* __restrict__ A) {
    int n = blockIdx.x * 256 + threadIdx.x;
    int b = n >> 10, hw = n & 1023;
    int c0 = blockIdx.y * 64;
    const float* zp = z + (size_t)b * 262144 + hw;
    #pragma unroll 8
    for (int c = c0; c < c0 + 64; ++c)
        zbf[(size_t)n * C_DIM + c] = f2bf(zp[(size_t)c * 1024]);
    if (blockIdx.y == 0) {
        float a = 0.0f;
        #pragma unroll 8
        for (int c = 0; c < C_DIM; ++c) {
            float v = zp[(size_t)c * 1024];
            a = fmaf(v, v, a);
        }
        A[n] = a;
    }
}

// ---------------------------------------------------------------------------
// Stage A: bf16 MFMA GEMM, 128n x 128j per block (4 waves, 2x2), K=256.
// 2-level XCD swizzle: XCD x owns by in [16x,16x+16); sweeps 8-bx j-stripes
// (instantaneous L2 set ~1.5 MB << 4 MB).  Reg-staged double-buffer: next
// chunk's global loads issue before the MFMAs -> latency hides under compute.
__global__ __launch_bounds__(256) void k_mfma(const unsigned short* __restrict__ zbf,
                                              const unsigned short* __restrict__ cbbf,
                                              float* __restrict__ tilemin) {
    __shared__ unsigned short As[128 * 72];   // [n][k]
    __shared__ unsigned short Bs[128 * 72];   // [j][k]
    __shared__ float smin[128][2];

    const int tid = threadIdx.x;
    const int lin = blockIdx.x;
    const int x = lin & 7, r = lin >> 3;                  // XCD, rank within
    const int jp = r >> 7, q = r & 127;
    const int by = x * 16 + (q >> 3), bx = jp * 8 + (q & 7);
    const int n0 = by * 128, j0 = bx * 128;
    const int wave = tid >> 6, lane = tid & 63;
    const int wx = wave & 1, wy = wave >> 1;              // wave tile: 64n x 64j
    const int g = lane >> 4, c = lane & 15;
    const int kg = tid & 7, nl = tid >> 3;                // staging decomposition

    short8v ra[4], rb[4];
    #pragma unroll
    for (int p = 0; p < 4; ++p) {
        int row = nl + 32 * p;
        ra[p] = *(const short8v*)&zbf[(size_t)(n0 + row) * C_DIM + kg * 8];
        rb[p] = *(const short8v*)&cbbf[(size_t)(j0 + row) * C_DIM + kg * 8];
    }

    f32x4 acc[4][4];
    #pragma unroll
    for (int i = 0; i < 4; ++i)
        #pragma unroll
        for (int j = 0; j < 4; ++j) acc[i][j] = (f32x4){0.f, 0.f, 0.f, 0.f};

    for (int kc = 0; kc < C_DIM; kc += 64) {
        __syncthreads();                                  // prev consumers done
        #pragma unroll
        for (int p = 0; p < 4; ++p) {
            int row = nl + 32 * p;
            *(short8v*)&As[row * 72 + kg * 8] = ra[p];
            *(short8v*)&Bs[row * 72 + kg * 8] = rb[p];
        }
        __syncthreads();
        if (kc < C_DIM - 64) {                            // prefetch next chunk
            #pragma unroll
            for (int p = 0; p < 4; ++p) {
                int row = nl + 32 * p;
                ra[p] = *(const short8v*)&zbf[(size_t)(n0 + row) * C_DIM + kc + 64 + kg * 8];
                rb[p] = *(const short8v*)&cbbf[(size_t)(j0 + row) * C_DIM + kc + 64 + kg * 8];
            }
        }

        #pragma unroll
        for (int kk = 0; kk < 64; kk += 32) {
            short8v a[4], b[4];
            #pragma unroll
            for (int f = 0; f < 4; ++f)
                a[f] = *(const short8v*)&As[(wy * 64 + f * 16 + c) * 72 + kk + g * 8];
            #pragma unroll
            for (int f = 0; f < 4; ++f)
                b[f] = *(const short8v*)&Bs[(wx * 64 + f * 16 + c) * 72 + kk + g * 8];
            #pragma unroll
            for (int nf = 0; nf < 4; ++nf)
                #pragma unroll
                for (int jf = 0; jf < 4; ++jf)
                    acc[nf][jf] = __builtin_amdgcn_mfma_f32_16x16x32_bf16(
                        a[nf], b[jf], acc[nf][jf], 0, 0, 0);
        }
    }

    // C layout: col = lane&15 (j), row = (lane>>4)*4 + reg (n).  max over j.
    #pragma unroll
    for (int nf = 0; nf < 4; ++nf) {
        #pragma unroll
        for (int rr = 0; rr < 4; ++rr) {
            float mx = acc[nf][0][rr];
            #pragma unroll
            for (int jf = 1; jf < 4; ++jf) mx = fmaxf(mx, acc[nf][jf][rr]);
            #pragma unroll
            for (int off = 1; off < 16; off <<= 1)
                mx = fmaxf(mx, __shfl_xor(mx, off, 64));
            if (c == 0) smin[wy * 64 + nf * 16 + g * 4 + rr][wx] = -2.0f * mx;
        }
    }
    __syncthreads();
    if (tid < 128)
        tilemin[(size_t)bx * N_VEC + n0 + tid] = fminf(smin[tid][0], smin[tid][1]);
}

// ---------------------------------------------------------------------------
// Stage B1a: thr[n] = min_t tilemin[t][n] + MARGIN; also re-arms keys[n].
__global__ __launch_bounds__(256) void k_rowmin(const float* __restrict__ tilemin,
                                               float* __restrict__ thr,
                                               unsigned long long* __restrict__ keys) {
    __shared__ float red[4][64];
    const int nl = threadIdx.x & 63, tg = threadIdx.x >> 6;
    const int n = blockIdx.x * 64 + nl;
    float m = 3.4e38f;
    #pragma unroll
    for (int i = 0; i < 16; ++i)
        m = fminf(m, tilemin[(size_t)(tg * 16 + i) * N_VEC + n]);
    red[tg][nl] = m;
    __syncthreads();
    if (tg == 0) {
        thr[n] = fminf(fminf(red[0][nl], red[1][nl]),
                       fminf(red[2][nl], red[3][nl])) + MARGIN;
        keys[n] = ~0ull;
    }
}

// ---------------------------------------------------------------------------
// Stage B1b: build per-tile candidate lists (wave-aggregated compaction).
__global__ __launch_bounds__(256) void k_build(const float* __restrict__ tilemin,
                                               const float* __restrict__ thr,
                                               int* __restrict__ listlen,
                                               int* __restrict__ lists) {
    const int t = blockIdx.x;
    const int lane = threadIdx.x & 63;
    #pragma unroll
    for (int it = 0; it < 8; ++it) {
        int n = blockIdx.y * 2048 + it * 256 + threadIdx.x;
        bool qq = tilemin[(size_t)t * N_VEC + n] <= thr[n];
        unsigned long long mask = __ballot(qq);
        if (mask) {
            int ldr = __ffsll(mask) - 1;
            int base = 0;
            if (lane == ldr) base = atomicAdd(&listlen[t], __popcll(mask));
            base = __shfl(base, ldr, 64);
            if (qq) {
                int pre = __popcll(mask & ((1ull << lane) - 1ull));
                lists[t * N_VEC + base + pre] = n;
            }
        }
    }
}

// ---------------------------------------------------------------------------
// Stage B2: tile-centric exact refine.  grid (64, 128).  Reads z directly in
// its original (B,C,H,W) layout (same values/order as the old zT copy).
__global__ __launch_bounds__(256) void k_refine2(const float* __restrict__ z,
                                                 const float* __restrict__ cb,
                                                 const float* __restrict__ ce,
                                                 const float* __restrict__ A,
                                                 const int* __restrict__ listlen,
                                                 const int* __restrict__ lists,
                                                 unsigned long long* __restrict__ keys) {
    __shared__ float e_s[128 * 68];
    __shared__ float z_s[32 * 68];
    __shared__ int   rows_s[32];

    const int t = blockIdx.x;
    const int len = listlen[t];
    const int tid = threadIdx.x;
    const int jg = tid & 31, rg = tid >> 5;
    const int j0 = t * 128;

    for (int b0 = blockIdx.y * 32; b0 < len; b0 += 128 * 32) {
        const int nrows = min(32, len - b0);
        __syncthreads();                           // protect prev batch's LDS
        if (tid < 32)
            rows_s[tid] = lists[t * N_VEC + b0 + min(tid, nrows - 1)];  // pad dup row0

        float acc[4][4];
        #pragma unroll
        for (int rr = 0; rr < 4; ++rr)
            #pragma unroll
            for (int jj = 0; jj < 4; ++jj) acc[rr][jj] = 0.0f;

        for (int kc = 0; kc < C_DIM; kc += 64) {
            __syncthreads();
            {   // stage e chunk: 128 j x 64 k
                int jr = tid >> 1, ko = (tid & 1) * 32;
                #pragma unroll
                for (int i = 0; i < 8; ++i)
                    *(float4*)&e_s[jr * 68 + ko + i * 4] =
                        *(const float4*)&cb[(size_t)(j0 + jr) * C_DIM + kc + ko + i * 4];
            }
            {   // stage z chunk: 32 rows x 64 k from original layout
                int rr = tid & 31, ks = tid >> 5;
                int n = rows_s[rr];
                int bb = n >> 10, hw = n & 1023;
                const float* zp = z + (size_t)bb * 262144 + hw;
                #pragma unroll
                for (int i = 0; i < 8; ++i) {
                    int k = kc + ks * 8 + i;
                    z_s[rr * 68 + ks * 8 + i] = zp[(size_t)k * 1024];
                }
            }
            __syncthreads();

            #pragma unroll
            for (int k4 = 0; k4 < 16; ++k4) {
                float4 ef[4], zf[4];
                #pragma unroll
                for (int jj = 0; jj < 4; ++jj)
                    ef[jj] = *(const float4*)&e_s[(jg + 32 * jj) * 68 + k4 * 4];
                #pragma unroll
                for (int rr = 0; rr < 4; ++rr)
                    zf[rr] = *(const float4*)&z_s[(rg * 4 + rr) * 68 + k4 * 4];
                #pragma unroll
                for (int kk = 0; kk < 4; ++kk)       // k ascending: exact chain
                    #pragma unroll
                    for (int rr = 0; rr < 4; ++rr)
                        #pragma unroll
                        for (int jj = 0; jj < 4; ++jj)
                            acc[rr][jj] = fmaf(((const float*)&zf[rr])[kk],
                                               ((const float*)&ef[jj])[kk], acc[rr][jj]);
            }
        }

        // epilogue: exact d, packed key, min over jj then over jg lanes
        #pragma unroll
        for (int rr = 0; rr < 4; ++rr) {
            const int n = rows_s[rg * 4 + rr];
            const float An = A[n];
            unsigned long long best = ~0ull;
            #pragma unroll
            for (int jj = 0; jj < 4; ++jj) {
                int j = j0 + jg + 32 * jj;
                float tt = An + ce[j];
                float d = fmaf(-2.0f, acc[rr][jj], tt);   // == R2 epilogue bits
                unsigned int sd = __float_as_uint(d);
                sd = (sd & 0x80000000u) ? ~sd : (sd | 0x80000000u);
                unsigned long long key = ((unsigned long long)sd << 32) | (unsigned)j;
                best = key < best ? key : best;
            }
            #pragma unroll
            for (int off = 16; off > 0; off >>= 1) {      // reduce 32 jg lanes
                unsigned long long o = __shfl_xor(best, off, 64);
                best = o < best ? o : best;
            }
            if (jg == 0) atomicMin(&keys[n], best);
        }
    }
}

// ---------------------------------------------------------------------------
// gather z_q + idx unpack + histogram + fp64 SSE reduction (combine merged)
__global__ __launch_bounds__(256) void k_gather(const float* __restrict__ z,
                                                const float* __restrict__ cb,
                                                const unsigned long long* __restrict__ keys,
                                                float* __restrict__ out,
                                                float* __restrict__ out_idx,
                                                int* __restrict__ counts,
                                                double* __restrict__ sse) {
    int bh = blockIdx.x;                 // b*32 + h
    int b = bh >> 5, h = bh & 31;
    int tid = threadIdx.x;
    __shared__ int sidx[32];
    if (tid < 32) {
        int n = b * 1024 + h * 32 + tid;
        unsigned long long k = keys[n];
        int idx = (int)(k & 0xFFFFFFFFull);
        sidx[tid] = idx;
        out_idx[n] = (float)idx;
        atomicAdd(&counts[idx], 1);
    }
    __syncthreads();
    int w = tid & 31, cy = tid >> 5;
    int jid = sidx[w];
    const float* cbr = cb + (size_t)jid * C_DIM;
    size_t zb = (size_t)b * 262144 + h * 32 + w;

    double acc = 0.0;
    #pragma unroll 4
    for (int cc = 0; cc < 32; ++cc) {
        int c = cc * 8 + cy;
        float e = cbr[c];
        size_t zi = zb + (size_t)c * 1024;
        float d = e - z[zi];
        out[zi] = e;
        acc += (double)(d * d);
    }
    #pragma unroll
    for (int off = 32; off > 0; off >>= 1) acc += __shfl_down(acc, off, 64);
    __shared__ double sh[4];
    if ((tid & 63) == 0) sh[tid >> 6] = acc;
    __syncthreads();
    if (tid == 0) atomicAdd(sse, sh[0] + sh[1] + sh[2] + sh[3]);
}

// ---------------------------------------------------------------------------
// Gram matrix M = Wn^T Wn  (256x256), j-split with float atomics
__global__ __launch_bounds__(256) void k_gram(const float* __restrict__ cb,
                                              const float* __restrict__ rn,
                                              float* __restrict__ M) {
    __shared__ float aT[64][68];
    __shared__ float bT[64][68];
    int k0 = blockIdx.x * 64, l0 = blockIdx.y * 64;
    int jc0 = blockIdx.z * 256;
    int tid = threadIdx.x;
    int tk = tid & 15, tl = tid >> 4;
    float acc[4][4];
    #pragma unroll
    for (int i = 0; i < 4; ++i)
        #pragma unroll
        for (int l = 0; l < 4; ++l) acc[i][l] = 0.0f;

    for (int jc = jc0; jc < jc0 + 256; jc += 64) {
        __syncthreads();
        {
            int kk = tid & 63, jj0 = tid >> 6;
            #pragma unroll
            for (int p = 0; p < 16; ++p) {
                int jj = p * 4 + jj0;
                float r = rn[jc + jj];
                const float* row = cb + (size_t)(jc + jj) * C_DIM;
                aT[jj][kk] = row[k0 + kk] * r;
                bT[jj][kk] = row[l0 + kk] * r;
            }
        }
        __syncthreads();
        #pragma unroll 8
        for (int jj = 0; jj < 64; ++jj) {
            float4 av = *(const float4*)&aT[jj][tk * 4];
            float4 bv = *(const float4*)&bT[jj][tl * 4];
            float a4[4] = {av.x, av.y, av.z, av.w};
            float b4[4] = {bv.x, bv.y, bv.z, bv.w};
            #pragma unroll
            for (int i = 0; i < 4; ++i)
                #pragma unroll
                for (int l = 0; l < 4; ++l)
                    acc[i][l] = fmaf(a4[i], b4[l], acc[i][l]);
        }
    }
    #pragma unroll
    for (int i = 0; i < 4; ++i)
        #pragma unroll
        for (int l = 0; l < 4; ++l)
            atomicAdd(&M[(size_t)(k0 + tk * 4 + i) * C_DIM + l0 + tl * 4 + l], acc[i][l]);
}

// ---------------------------------------------------------------------------
// finalize scalars: loss, ortho = (||M||_F^2 - n_e)/n_e^2, perplexity
__global__ __launch_bounds__(256) void k_final(const float* __restrict__ M,
                                               const int* __restrict__ counts,
                                               const double* __restrict__ accum,
                                               float* __restrict__ out_scalars) {
    int tid = threadIdx.x;
    __shared__ double sh[4];

    double s = 0.0;
    for (int i = tid; i < C_DIM * C_DIM; i += 256) {
        double m = M[i];
        s += m * m;
    }
    #pragma unroll
    for (int off = 32; off > 0; off >>= 1) s += __shfl_down(s, off, 64);
    if ((tid & 63) == 0) sh[tid >> 6] = s;
    __syncthreads();
    double S = sh[0] + sh[1] + sh[2] + sh[3];
    __syncthreads();

    double H = 0.0;
    for (int j = tid; j < N_E; j += 256) {
        double p = counts[j] * (1.0 / (double)N_VEC);
        H += p * log(p + 1e-10);
    }
    #pragma unroll
    for (int off = 32; off > 0; off >>= 1) H += __shfl_down(H, off, 64);
    if ((tid & 63) == 0) sh[tid >> 6] = H;
    __syncthreads();

    if (tid == 0) {
        double Hs = sh[0] + sh[1] + sh[2] + sh[3];
        out_scalars[0] = (float)(1.25 * accum[0] / (double)N_ELEM);        // loss
        out_scalars[1] = (float)((S - (double)N_E) / ((double)N_E * N_E)); // ortho
        out_scalars[2] = (float)exp(-Hs);                                  // perplexity
    }
}

// ---------------------------------------------------------------------------
extern "C" void kernel_launch(void* const* d_in, const int* in_sizes, int n_in,
                              void* d_out, int out_size, void* d_ws, size_t ws_size,
                              hipStream_t stream) {
    (void)in_sizes; (void)n_in; (void)out_size; (void)ws_size;
    const float* z  = (const float*)d_in[0];
    const float* cb = (const float*)d_in[1];
    float* out = (float*)d_out;

    char* ws = (char*)d_ws;
    int* counts            = (int*)(ws + WS_COUNTS);
    float* M               = (float*)(ws + WS_M);
    double* accum          = (double*)(ws + WS_ACCUM);
    int* listlen           = (int*)(ws + WS_LISTLEN);
    float* ce              = (float*)(ws + WS_CE);
    float* rn              = (float*)(ws + WS_RN);
    float* A               = (float*)(ws + WS_A);
    unsigned long long* keys = (unsigned long long*)(ws + WS_KEYS);
    int* lists             = (int*)(ws + WS_LISTS);
    float* tilemin         = (float*)(ws + WS_TILEMIN);
    unsigned short* zbf    = (unsigned short*)(ws + WS_ZBF);
    unsigned short* cbbf   = (unsigned short*)(ws + WS_CBBF);
    float* thr             = (float*)(ws + WS_THR);

    float* out_scalars = out + N_ELEM;       // loss, ortho, perplexity
    float* out_idx     = out + N_ELEM + 3;   // 16384 idx as float

    hipMemsetAsync(ws, 0, WS_ZERO_BYTES, stream);   // counts + M + accum + listlen

    k_cbprep<<<N_E, 256, 0, stream>>>(cb, ce, rn, cbbf);
    k_ztrans<<<dim3(N_VEC / 256, 4), 256, 0, stream>>>(z, zbf, A);
    k_mfma<<<8192, 256, 0, stream>>>(zbf, cbbf, tilemin);
    k_rowmin<<<N_VEC / 64, 256, 0, stream>>>(tilemin, thr, keys);
    k_build<<<dim3(64, 8), 256, 0, stream>>>(tilemin, thr, listlen, lists);
    k_refine2<<<dim3(64, 128), 256, 0, stream>>>(z, cb, ce, A, listlen, lists, keys);
    k_gather<<<512, 256, 0, stream>>>(z, cb, keys, out, out_idx, counts, accum);
    k_gram<<<dim3(4, 4, 32), 256, 0, stream>>>(cb, rn, M);
    k_final<<<1, 256, 0, stream>>>(M, counts, accum, out_scalars);
}